// Round 10
// baseline (48.256 us; speedup 1.0000x reference)
//
#include <hip/hip_runtime.h>

#define NROWS 4096
#define NCOLS 10000
#define NLAT  64
#define TPB   256
#define NBX   5                 /* column blocks in K1 */
#define COLB  2000              /* columns per K1 block (500 float4 slots) */
#define SLOT2 (COLB / 4 - 256)  /* 244 threads own a second slot */
#define NRC   256               /* row chunks: 5*256 = 1280 blocks = 5/CU */
#define RPC   16                /* rows per chunk */
#define NCB   40                /* column blocks in fold */
#define CPB   250               /* columns per fold block */
#define NSLICE 32               /* chunk slices in fold */
#define CPS   (NRC / NSLICE)    /* 8 chunks per slice */
#define NBLK2 (NCB * NSLICE)    /* 1280 fold blocks = 5/CU */

// K1: streaming pass over X. ONE variable changed vs the 42.8us R6 kernel:
// per-row burst per block is 8KB contiguous (COLB=2000, thread owns slots
// t and t+256) instead of 4KB — testing whether the 4KB@40KB-stride pattern
// was costing ~15% of read BW. Grid 1280 = 5/CU exact; accumulators kept in
// 16 VGPRs so 20 waves/CU co-residency holds. Fixed slots, deterministic.
__global__ __launch_bounds__(TPB) void colsum_partials(
        const float* __restrict__ X,
        float* __restrict__ ps, float* __restrict__ ps2) {
    const int bx = blockIdx.x, by = blockIdx.y, t = threadIdx.x;
    const float* rowp = X + (size_t)by * RPC * NCOLS + (size_t)bx * COLB;
    float4 s0 = make_float4(0.f, 0.f, 0.f, 0.f), s1 = s0, q0 = s0, q1 = s0;
    #pragma unroll 4
    for (int r = 0; r < RPC; ++r) {
        float4 a = *reinterpret_cast<const float4*>(rowp + (size_t)t * 4);
        s0.x += a.x; s0.y += a.y; s0.z += a.z; s0.w += a.w;
        q0.x = fmaf(a.x, a.x, q0.x); q0.y = fmaf(a.y, a.y, q0.y);
        q0.z = fmaf(a.z, a.z, q0.z); q0.w = fmaf(a.w, a.w, q0.w);
        if (t < SLOT2) {
            float4 b = *reinterpret_cast<const float4*>(rowp + (size_t)(256 + t) * 4);
            s1.x += b.x; s1.y += b.y; s1.z += b.z; s1.w += b.w;
            q1.x = fmaf(b.x, b.x, q1.x); q1.y = fmaf(b.y, b.y, q1.y);
            q1.z = fmaf(b.z, b.z, q1.z); q1.w = fmaf(b.w, b.w, q1.w);
        }
        rowp += NCOLS;
    }
    size_t o = (size_t)by * NCOLS + (size_t)bx * COLB;
    *reinterpret_cast<float4*>(ps  + o + (size_t)t * 4) = s0;
    *reinterpret_cast<float4*>(ps2 + o + (size_t)t * 4) = q0;
    if (t < SLOT2) {
        *reinterpret_cast<float4*>(ps  + o + (size_t)(256 + t) * 4) = s1;
        *reinterpret_cast<float4*>(ps2 + o + (size_t)(256 + t) * 4) = q1;
    }
}

// K2: fold 8 chunks + one coalesced V sweep -> t[64]-partial + q-partial per
// block, TRANSPOSED output tpT[f][bid] (row 64 = q). Same structure as R6;
// NSLICE=32 absorbs the doubled chunk count (1280 blocks = 5/CU).
__global__ __launch_bounds__(TPB) void fold_qt(
        const float* __restrict__ ps, const float* __restrict__ ps2,
        const float* __restrict__ V, float* __restrict__ tpT) {
    const int cb = blockIdx.x;          // 0..39
    const int sl = blockIdx.y;          // 0..31
    const int tid = threadIdx.x;
    __shared__ float lds_s[CPB], lds_s2[CPB];
    if (tid < CPB) {
        const int col = cb * CPB + tid;
        float s = 0.f, s2 = 0.f;
        const int c0 = sl * CPS;
        #pragma unroll
        for (int c = c0; c < c0 + CPS; ++c) {        // coalesced 1KB runs
            s  += ps [(size_t)c * NCOLS + col];
            s2 += ps2[(size_t)c * NCOLS + col];
        }
        lds_s[tid] = s; lds_s2[tid] = s2;
    }
    __syncthreads();

    const int lane = tid & 63, w = tid >> 6;
    float at = 0.f, aq = 0.f;
    const float* Vb = V + (size_t)cb * CPB * NLAT;
    #pragma unroll 4
    for (int c = w; c < CPB; c += 4) {
        float v = Vb[(size_t)c * NLAT + lane];       // 256B/wave, L2-hit
        at = fmaf(lds_s[c], v, at);
        aq = fmaf(lds_s2[c], v * v, aq);
    }
    #pragma unroll
    for (int st = 1; st < 64; st <<= 1) aq += __shfl_xor(aq, st, 64);

    __shared__ float lt[4][NLAT];
    __shared__ float lq[4];
    lt[w][lane] = at;
    if (lane == 0) lq[w] = aq;
    __syncthreads();

    const int bid = sl * NCB + cb;                   // 0..1279
    if (tid < NLAT)
        tpT[(size_t)tid * NBLK2 + bid] = lt[0][tid] + lt[1][tid]
                                       + lt[2][tid] + lt[3][tid];
    if (tid == 0)
        tpT[(size_t)NLAT * NBLK2 + bid] = lq[0] + lq[1] + lq[2] + lq[3];
}

// K3: out = 0.5*(sum_f t[f]^2 - q). 16 waves; wave w reduces contiguous
// 5.12KB rows (coalesced 256B steps + butterfly). No fences/atomics
// (R4 lesson: device-scope fences on 8 XCDs cost ~100x a launch boundary).
__global__ __launch_bounds__(1024) void finalize(
        const float* __restrict__ tpT, float* __restrict__ out) {
    const int tid = threadIdx.x, lane = tid & 63, w = tid >> 6;
    __shared__ float red[NLAT + 1];
    for (int r = w; r < NLAT + 1; r += 16) {
        const float* row = tpT + (size_t)r * NBLK2;
        float a = 0.f;
        #pragma unroll
        for (int i = 0; i < NBLK2 / 64; ++i) a += row[i * 64 + lane];
        #pragma unroll
        for (int st = 1; st < 64; st <<= 1) a += __shfl_xor(a, st, 64);
        if (lane == 0) red[r] = a;
    }
    __syncthreads();
    if (w == 0) {
        float t = red[lane];
        float d = t * t;
        #pragma unroll
        for (int st = 1; st < 64; st <<= 1) d += __shfl_xor(d, st, 64);
        if (lane == 0) out[0] = 0.5f * (d - red[NLAT]);
    }
}

extern "C" void kernel_launch(void* const* d_in, const int* in_sizes, int n_in,
                              void* d_out, int out_size, void* d_ws, size_t ws_size,
                              hipStream_t stream) {
    const float* X = (const float*)d_in[0];   // [4096, 10000] f32
    const float* V = (const float*)d_in[1];   // [10000, 64]  f32
    float* out = (float*)d_out;               // scalar f32

    float* ps  = (float*)d_ws;                         // [NRC][NCOLS]
    float* ps2 = ps  + (size_t)NRC * NCOLS;            // [NRC][NCOLS]
    float* tpT = ps2 + (size_t)NRC * NCOLS;            // [NLAT+1][NBLK2]

    colsum_partials<<<dim3(NBX, NRC), TPB, 0, stream>>>(X, ps, ps2);
    fold_qt<<<dim3(NCB, NSLICE), TPB, 0, stream>>>(ps, ps2, V, tpT);
    finalize<<<1, 1024, 0, stream>>>(tpT, out);
}

// Round 11
// 42.879 us; speedup vs baseline: 1.1254x; 1.1254x over previous
//
#include <hip/hip_runtime.h>

#define NROWS 4096
#define NCOLS 10000
#define NLAT  64
#define NCOLG 2500              /* NCOLS / 4 */
#define TPB   256
#define NBX   10                /* column blocks in K1 */
#define NRC   128               /* row chunks: 10*128 = 1280 blocks = 5/CU */
#define RPC   32                /* rows per chunk */
#define NCB   40                /* column blocks in fold */
#define CPB   250               /* columns per fold block */
#define NSLICE 16               /* chunk slices in fold */
#define CPS   (NRC / NSLICE)    /* 8 chunks per slice */
#define NBLK2 (NCB * NSLICE)    /* 640 fold blocks */

// FINAL (R6 structure, measured 42.8/43.0 us twice).
// K1: pure streaming pass over X (163.84 MB). Thread owns 4 consecutive
// columns (float4, 1024B/wave coalesced); block-row y covers 32 rows;
// writes partial colsum/colsum^2 to fixed slots. 1280 blocks = 5/CU exact.
// Tested and rejected: 2-chain ILP (R8 neutral -> not latency-limited),
// 8KB bursts (R10 -5us), 10 blocks/CU (R7, breaks 32-wave cap), fused
// V-sweep (R5, V evicted from L2 by X stream), last-block fence finalize
// (R4, device-scope fences on 8 XCDs ~100x a launch boundary).
__global__ __launch_bounds__(TPB) void colsum_partials(
        const float* __restrict__ X,
        float* __restrict__ ps, float* __restrict__ ps2) {
    int jg = blockIdx.x * TPB + threadIdx.x;          // column group
    if (jg >= NCOLG) return;
    const float* p = X + (size_t)blockIdx.y * RPC * NCOLS + (size_t)jg * 4;
    float s0=0.f,s1=0.f,s2=0.f,s3=0.f,q0=0.f,q1=0.f,q2=0.f,q3=0.f;
    #pragma unroll 8
    for (int r = 0; r < RPC; ++r) {
        float4 v = *reinterpret_cast<const float4*>(p);
        p += NCOLS;
        s0 += v.x; s1 += v.y; s2 += v.z; s3 += v.w;
        q0 = fmaf(v.x, v.x, q0); q1 = fmaf(v.y, v.y, q1);
        q2 = fmaf(v.z, v.z, q2); q3 = fmaf(v.w, v.w, q3);
    }
    size_t o = (size_t)blockIdx.y * NCOLS + (size_t)jg * 4;
    *reinterpret_cast<float4*>(ps  + o) = make_float4(s0, s1, s2, s3);
    *reinterpret_cast<float4*>(ps2 + o) = make_float4(q0, q1, q2, q3);
}

// K2: fold 8 chunks + one coalesced V sweep -> t[64]-partial + q-partial per
// block, TRANSPOSED output tpT[f][bid] (row 64 = q). Lane = latent f; V reads
// 256B/wave coalesced; lds_s[c] wave-uniform broadcast. Fixed order ->
// deterministic. 640 blocks (R2 lesson: the fold must not be wave-starved).
__global__ __launch_bounds__(TPB) void fold_qt(
        const float* __restrict__ ps, const float* __restrict__ ps2,
        const float* __restrict__ V, float* __restrict__ tpT) {
    const int cb = blockIdx.x;          // 0..39
    const int sl = blockIdx.y;          // 0..15
    const int tid = threadIdx.x;
    __shared__ float lds_s[CPB], lds_s2[CPB];
    if (tid < CPB) {
        const int col = cb * CPB + tid;
        float s = 0.f, s2 = 0.f;
        const int c0 = sl * CPS;
        #pragma unroll
        for (int c = c0; c < c0 + CPS; ++c) {        // coalesced 1KB runs
            s  += ps [(size_t)c * NCOLS + col];
            s2 += ps2[(size_t)c * NCOLS + col];
        }
        lds_s[tid] = s; lds_s2[tid] = s2;
    }
    __syncthreads();

    const int lane = tid & 63, w = tid >> 6;
    float at = 0.f, aq = 0.f;
    const float* Vb = V + (size_t)cb * CPB * NLAT;
    #pragma unroll 4
    for (int c = w; c < CPB; c += 4) {
        float v = Vb[(size_t)c * NLAT + lane];       // 256B/wave, L2-hit
        at = fmaf(lds_s[c], v, at);
        aq = fmaf(lds_s2[c], v * v, aq);
    }
    #pragma unroll
    for (int st = 1; st < 64; st <<= 1) aq += __shfl_xor(aq, st, 64);

    __shared__ float lt[4][NLAT];
    __shared__ float lq[4];
    lt[w][lane] = at;
    if (lane == 0) lq[w] = aq;
    __syncthreads();

    const int bid = sl * NCB + cb;                   // 0..639
    if (tid < NLAT)
        tpT[(size_t)tid * NBLK2 + bid] = lt[0][tid] + lt[1][tid]
                                       + lt[2][tid] + lt[3][tid];
    if (tid == 0)
        tpT[(size_t)NLAT * NBLK2 + bid] = lq[0] + lq[1] + lq[2] + lq[3];
}

// K3: out = 0.5*(sum_f t[f]^2 - q). 16 waves; wave w reduces contiguous
// 2.56KB rows r = w, w+16, ... (coalesced 256B steps + butterfly).
__global__ __launch_bounds__(1024) void finalize(
        const float* __restrict__ tpT, float* __restrict__ out) {
    const int tid = threadIdx.x, lane = tid & 63, w = tid >> 6;
    __shared__ float red[NLAT + 1];
    for (int r = w; r < NLAT + 1; r += 16) {
        const float* row = tpT + (size_t)r * NBLK2;
        float a = 0.f;
        #pragma unroll
        for (int i = 0; i < NBLK2 / 64; ++i) a += row[i * 64 + lane];
        #pragma unroll
        for (int st = 1; st < 64; st <<= 1) a += __shfl_xor(a, st, 64);
        if (lane == 0) red[r] = a;
    }
    __syncthreads();
    if (w == 0) {
        float t = red[lane];
        float d = t * t;
        #pragma unroll
        for (int st = 1; st < 64; st <<= 1) d += __shfl_xor(d, st, 64);
        if (lane == 0) out[0] = 0.5f * (d - red[NLAT]);
    }
}

extern "C" void kernel_launch(void* const* d_in, const int* in_sizes, int n_in,
                              void* d_out, int out_size, void* d_ws, size_t ws_size,
                              hipStream_t stream) {
    const float* X = (const float*)d_in[0];   // [4096, 10000] f32
    const float* V = (const float*)d_in[1];   // [10000, 64]  f32
    float* out = (float*)d_out;               // scalar f32

    float* ps  = (float*)d_ws;                         // [NRC][NCOLS]
    float* ps2 = ps  + (size_t)NRC * NCOLS;            // [NRC][NCOLS]
    float* tpT = ps2 + (size_t)NRC * NCOLS;            // [NLAT+1][NBLK2]

    colsum_partials<<<dim3(NBX, NRC), TPB, 0, stream>>>(X, ps, ps2);
    fold_qt<<<dim3(NCB, NSLICE), TPB, 0, stream>>>(ps, ps2, V, tpT);
    finalize<<<1, 1024, 0, stream>>>(tpT, out);
}